// Round 7
// baseline (453.027 us; speedup 1.0000x reference)
//
#include <hip/hip_runtime.h>

#define N_USERS 60000
#define N_ITEMS 40000
#define N_TOTAL 100000
#define EMB 64
#define LN_EPS 1e-5f

#define KPS 128                                  // keys (dest rows) per super-bucket
#define KSH 7                                    // log2(KPS)
#define NSUP ((N_TOTAL + KPS - 1) / KPS)         // 782
#define EPB 2048                                 // edges per build block (r7: 4096->2048 for 4 blk/CU)
#define BLT 512                                  // build threads (8 waves)
#define EPT (EPB / BLT)                          // 4 edges per thread
#define TR_ROWS 32                               // rows per transform block
#define XPITCH 68                                // x-tile pitch (floats)
#define CAP 2048                                 // edges per LDS sort chunk
#define SPT 512                                  // spmm_fused threads (8 waves)

// bf16 helpers (exact shift for bf16->f32; RNE for f32->bf16)
__device__ __forceinline__ float bf2f(unsigned short h)
{ return __uint_as_float(((unsigned)h) << 16); }
__device__ __forceinline__ unsigned short f2bf(float f)
{
    unsigned u = __float_as_uint(f);
    return (unsigned short)((u + 0x7FFFu + ((u >> 16) & 1u)) >> 16);
}

// ---------------------------------------------------------------------------
// ego2[r,:] = c * filt[r] * (x[r,:] @ W) + x[r,:]   (bf16 output)
__global__ void transform_tile(const float* __restrict__ x,
                               const float* __restrict__ w_uu,
                               const float* __restrict__ filt_uu,
                               const float* __restrict__ par_uu,
                               const float* __restrict__ w_ii,
                               const float* __restrict__ filt_ii,
                               const float* __restrict__ par_ii,
                               unsigned short* __restrict__ out)
{
    __shared__ float Wls[EMB * EMB];             // 16 KB
    __shared__ float xs[TR_ROWS * XPITCH];       // 8.7 KB
    const int tid = threadIdx.x;
    const int r0 = blockIdx.x * TR_ROWS;
    const int itm = (r0 >= N_USERS);             // uniform per block
    const float* W  = itm ? w_ii : w_uu;
    const float* fb = itm ? filt_ii : filt_uu;
    const int foff  = itm ? N_USERS : 0;
    const float c   = itm ? par_ii[0] * par_ii[1] : par_uu[0] * par_uu[1];

    for (int i = tid; i < EMB * EMB / 4; i += 256)
        ((float4*)Wls)[i] = ((const float4*)W)[i];
    for (int i = tid; i < TR_ROWS * 16; i += 256) {
        const float4 v = ((const float4*)x)[r0 * 16 + i];
        *(float4*)&xs[(i >> 4) * XPITCH + (i & 15) * 4] = v;
    }
    __syncthreads();

    const int lane = tid & 63;
    const int wv = tid >> 6;
    const int rg = lane >> 4;
    const int j  = lane & 15;

#pragma unroll
    for (int it = 0; it < 2; ++it) {
        const int rl = wv * 8 + it * 4 + rg;
        const int row = r0 + rl;
        float4 acc = make_float4(0.f, 0.f, 0.f, 0.f);
#pragma unroll 8
        for (int k = 0; k < EMB; ++k) {
            const float xb = xs[rl * XPITCH + k];
            const float4 w4 = *(const float4*)&Wls[k * EMB + 4 * j];
            acc.x += xb * w4.x; acc.y += xb * w4.y;
            acc.z += xb * w4.z; acc.w += xb * w4.w;
        }
        const float cf = c * fb[row - foff];
        const float4 xv = *(const float4*)&xs[rl * XPITCH + 4 * j];
        ushort4 o;
        o.x = f2bf(cf * acc.x + xv.x);
        o.y = f2bf(cf * acc.y + xv.y);
        o.z = f2bf(cf * acc.z + xv.z);
        o.w = f2bf(cf * acc.w + xv.w);
        *(ushort4*)&out[(size_t)row * EMB + 4 * j] = o;
    }
}

// ---------------------------------------------------------------------------
// Super-bucket histograms for BOTH orderings, int4-vectorized input loads.
__global__ void hist_sup(const int* __restrict__ rows,
                         const int* __restrict__ cols,
                         int* __restrict__ cnt_r,
                         int* __restrict__ cnt_c, int nnz)
{
    __shared__ int hr[NSUP], hc[NSUP];
    const int tid = threadIdx.x;
    for (int i = tid; i < NSUP; i += 256) { hr[i] = 0; hc[i] = 0; }
    __syncthreads();
    const int nq = nnz >> 2;
    for (int q = blockIdx.x * 256 + tid; q < nq; q += gridDim.x * 256) {
        const int4 r4 = ((const int4*)rows)[q];
        const int4 c4 = ((const int4*)cols)[q];
        atomicAdd(&hr[r4.x >> KSH], 1); atomicAdd(&hc[c4.x >> KSH], 1);
        atomicAdd(&hr[r4.y >> KSH], 1); atomicAdd(&hc[c4.y >> KSH], 1);
        atomicAdd(&hr[r4.z >> KSH], 1); atomicAdd(&hc[c4.z >> KSH], 1);
        atomicAdd(&hr[r4.w >> KSH], 1); atomicAdd(&hc[c4.w >> KSH], 1);
    }
    for (int e = (nq << 2) + blockIdx.x * 256 + tid; e < nnz; e += gridDim.x * 256) {
        atomicAdd(&hr[rows[e] >> KSH], 1);
        atomicAdd(&hc[cols[e] >> KSH], 1);
    }
    __syncthreads();
    for (int i = tid; i < NSUP; i += 256) {
        if (hr[i]) atomicAdd(&cnt_r[i], hr[i]);
        if (hc[i]) atomicAdd(&cnt_c[i], hc[i]);
    }
}

// Exclusive scan of the NSUP counters (NSUP <= 1024). grid=2: blk0=cols, 1=rows.
__global__ void scan_sup(const int* __restrict__ cnt_c, int* __restrict__ base_c,
                         int* __restrict__ cur_c,
                         const int* __restrict__ cnt_r, int* __restrict__ base_r,
                         int* __restrict__ cur_r)
{
    const int* cnt = blockIdx.x ? cnt_r : cnt_c;
    int* base = blockIdx.x ? base_r : base_c;
    int* cur  = blockIdx.x ? cur_r  : cur_c;
    __shared__ int wsum[16];
    const int i = threadIdx.x;                   // 1024 threads = 16 waves
    const int lane = i & 63;
    const int wv = i >> 6;
    const int v = (i < NSUP) ? cnt[i] : 0;
    int incl = v;
#pragma unroll
    for (int off = 1; off < 64; off <<= 1) {
        const int t = __shfl_up(incl, off, 64);
        if (lane >= off) incl += t;
    }
    if (lane == 63) wsum[wv] = incl;
    __syncthreads();
    if (i == 0) {
        int run = 0;
#pragma unroll
        for (int w = 0; w < 16; ++w) { const int t = wsum[w]; wsum[w] = run; run += t; }
        base[NSUP] = run;
    }
    __syncthreads();
    const int excl = wsum[wv] + incl - v;
    if (i < NSUP) { base[i] = excl; cur[i] = excl; }
}

// ---------------------------------------------------------------------------
// Fused dual-ordering grouping. Round-7 changes vs round-6:
//  - EPB 4096->2048: LDS 53.8->33 KB => 4 blocks/CU = 32 waves/CU (was 2/16,
//    Occupancy 53%, VALUBusy 4.7% -> pure latency bound; doubling residency
//    is the fix).
//  - goff[g] = gbase[g] - sexcl[g] folded at scan time: emit does ONE indexed
//    LDS read (goff) instead of two (gbase, hist) -> halves the indexed-read
//    bank conflicts (2.49M measured).
__global__ void __launch_bounds__(BLT, 8)
build_both(const int* __restrict__ rows,
           const int* __restrict__ cols,
           const float* __restrict__ vals,
           int* __restrict__ cur_c, int2* __restrict__ pairs_c,
           int* __restrict__ cur_r, int2* __restrict__ pairs_r, int nnz)
{
    __shared__ int2 stage[EPB];                  // 16 KB
    __shared__ unsigned short sg[EPB];           // 4 KB
    __shared__ int hist_c[NSUP];                 // counts (both kept live)
    __shared__ int hist_r[NSUP];
    __shared__ int goff[NSUP];                   // gbase - sexcl (per pass)
    __shared__ int lcur[NSUP];                   // running sexcl (per pass)
    __shared__ int wsum[8];

    const int tid = threadIdx.x;
    const int e0 = blockIdx.x * EPB;
    const int ecnt = min(EPB, nnz - e0);

    for (int i = tid; i < NSUP; i += BLT) { hist_c[i] = 0; hist_r[i] = 0; }
    __syncthreads();

    int myr[EPT], myc[EPT];
    float myv[EPT];
#pragma unroll
    for (int i = 0; i < EPT; ++i) {
        const int s = tid + i * BLT;
        if (s < ecnt) {
            const int e = e0 + s;
            myr[i] = rows[e]; myc[i] = cols[e]; myv[i] = vals[e];
            atomicAdd(&hist_c[myc[i] >> KSH], 1);   // two independent chains
            atomicAdd(&hist_r[myr[i] >> KSH], 1);
        } else myr[i] = -1;
    }
    __syncthreads();

    // ---- two passes: p=0 keyed by col -> pairs_c, p=1 keyed by row -------
#pragma unroll 1
    for (int p = 0; p < 2; ++p) {
        const int* hist = p ? hist_r : hist_c;
        int* gcur = p ? cur_r  : cur_c;
        int2* out = p ? pairs_r : pairs_c;

        // exclusive scan of hist[0..NSUP): thread t owns entries 2t, 2t+1
        {
            const int lane = tid & 63;
            const int wv = tid >> 6;             // 0..7
            const int i0 = tid * 2;
            const int va = (i0     < NSUP) ? hist[i0]     : 0;
            const int vb = (i0 + 1 < NSUP) ? hist[i0 + 1] : 0;
            const int tsum = va + vb;
            int incl = tsum;
#pragma unroll
            for (int off = 1; off < 64; off <<= 1) {
                const int t = __shfl_up(incl, off, 64);
                if (lane >= off) incl += t;
            }
            if (lane == 63) wsum[wv] = incl;
            __syncthreads();
            int woff = 0;
            for (int w = 0; w < wv; ++w) woff += wsum[w];
            const int excl = woff + incl - tsum;
            if (i0 < NSUP) {
                const int gb = va ? atomicAdd(&gcur[i0], va) : 0;
                lcur[i0] = excl;
                goff[i0] = gb - excl;
            }
            if (i0 + 1 < NSUP) {
                const int gb = vb ? atomicAdd(&gcur[i0 + 1], vb) : 0;
                lcur[i0 + 1] = excl + va;
                goff[i0 + 1] = gb - (excl + va);
            }
        }
        __syncthreads();

        // scatter into stage, grouped by this ordering's super-bucket
#pragma unroll
        for (int i = 0; i < EPT; ++i) {
            if (myr[i] >= 0) {
                const int key   = p ? myr[i] : myc[i];
                const int other = p ? myc[i] : myr[i];
                const int g = key >> KSH;
                const int s = atomicAdd(&lcur[g], 1);
                stage[s] = make_int2(other | ((key & (KPS - 1)) << 20),
                                     __float_as_int(myv[i]));
                sg[s] = (unsigned short)g;
            }
        }
        __syncthreads();

        // emit grouped bursts: one indexed LDS read per edge
        for (int s = tid; s < ecnt; s += BLT)
            out[goff[sg[s]] + s] = stage[s];
        __syncthreads();                         // stage/goff/lcur reuse
    }
}

// ---------------------------------------------------------------------------
// Fused LDS counting-sort + register pull. One 512-thread block per 128-row
// super-bucket (782 blocks, 33.5 KB LDS). Chunks of CAP edges: stage ->
// int-atomic hist -> wave-0 scan -> LDS scatter -> per-group register pull
// (16-lane group owns 4 rows; acc persists across chunks). 8/4/1 unroll
// ladder in the consume loop for memory-level parallelism.
// (Round-2 lesson: no LDS FP atomics — wave64 ds_add_f32 ~260 cy/instr.)
template <bool LN>
__global__ void __launch_bounds__(SPT, 6)
spmm_fused(const int* __restrict__ base,
           const int2* __restrict__ pairs,
           const unsigned short* __restrict__ src,
           const float* __restrict__ ego,
           const float* __restrict__ gamma,
           const float* __restrict__ beta,
           unsigned short* __restrict__ dstb,
           float* __restrict__ dstf)
{
    __shared__ int2 stage[CAP];                  // 16 KB
    __shared__ int2 sorted[CAP];                 // 16 KB
    __shared__ int cnt[KPS];                     // 512 B
    __shared__ int kbase[KPS];                   // 512 B
    __shared__ int kcur[KPS];                    // 512 B

    const int tid = threadIdx.x;
    const int sup = blockIdx.x;
    const int beg = base[sup];
    const int end = base[sup + 1];
    const int g = tid >> 4;                      // 32 groups of 16 lanes
    const int l = tid & 15;

    float4 acc[4];
#pragma unroll
    for (int i = 0; i < 4; ++i) acc[i] = make_float4(0.f, 0.f, 0.f, 0.f);

    if (tid < KPS) cnt[tid] = 0;
    __syncthreads();

    int c0 = beg;
    int csz = min(CAP, end - c0);
    for (int i = tid; i < csz; i += SPT) {
        const int2 v = pairs[c0 + i];
        stage[i] = v;
        atomicAdd(&cnt[(v.x >> 20) & (KPS - 1)], 1);
    }
    __syncthreads();

    while (csz > 0) {
        // ---- scan of 128 counters by wave 0 (lane owns 2 keys) -----------
        if (tid < 64) {
            const int ca = cnt[tid * 2];
            const int cb = cnt[tid * 2 + 1];
            const int tsum = ca + cb;
            int incl = tsum;
#pragma unroll
            for (int off = 1; off < 64; off <<= 1) {
                const int t = __shfl_up(incl, off, 64);
                if (tid >= off) incl += t;
            }
            const int run = incl - tsum;
            kbase[tid * 2] = run;          kcur[tid * 2] = run;
            kbase[tid * 2 + 1] = run + ca; kcur[tid * 2 + 1] = run + ca;
            cnt[tid * 2] = 0; cnt[tid * 2 + 1] = 0;   // ready for next hist
        }
        __syncthreads();

        // ---- counting-sort scatter (int LDS atomics: fast path) ----------
        for (int i = tid; i < csz; i += SPT) {
            const int2 v = stage[i];
            const int pos = atomicAdd(&kcur[(v.x >> 20) & (KPS - 1)], 1);
            sorted[pos] = v;
        }
        __syncthreads();

        // ---- consume (register pull, 8/4/1 ladder) + stage next chunk ----
        const int nc0 = c0 + csz;
        const int ncsz = min(CAP, end - nc0);

#pragma unroll
        for (int rr = 0; rr < 4; ++rr) {
            const int k = g * 4 + rr;
            int j = kbase[k];
            const int e = kcur[k];               // == end of key's run
            float4 a = acc[rr];
            for (; j + 8 <= e; j += 8) {
                int2 p[8]; ushort4 s[8];
#pragma unroll
                for (int u = 0; u < 8; ++u) p[u] = sorted[j + u];
#pragma unroll
                for (int u = 0; u < 8; ++u)
                    s[u] = ((const ushort4*)(src + (size_t)(p[u].x & 0x1FFFF) * EMB))[l];
#pragma unroll
                for (int u = 0; u < 8; ++u) {
                    const float v = __int_as_float(p[u].y);
                    a.x += v * bf2f(s[u].x); a.y += v * bf2f(s[u].y);
                    a.z += v * bf2f(s[u].z); a.w += v * bf2f(s[u].w);
                }
            }
            for (; j + 4 <= e; j += 4) {
                int2 p[4]; ushort4 s[4];
#pragma unroll
                for (int u = 0; u < 4; ++u) p[u] = sorted[j + u];
#pragma unroll
                for (int u = 0; u < 4; ++u)
                    s[u] = ((const ushort4*)(src + (size_t)(p[u].x & 0x1FFFF) * EMB))[l];
#pragma unroll
                for (int u = 0; u < 4; ++u) {
                    const float v = __int_as_float(p[u].y);
                    a.x += v * bf2f(s[u].x); a.y += v * bf2f(s[u].y);
                    a.z += v * bf2f(s[u].z); a.w += v * bf2f(s[u].w);
                }
            }
            for (; j < e; ++j) {
                const int2 p = sorted[j];
                const ushort4 s = ((const ushort4*)(src + (size_t)(p.x & 0x1FFFF) * EMB))[l];
                const float v = __int_as_float(p.y);
                a.x += v * bf2f(s.x); a.y += v * bf2f(s.y);
                a.z += v * bf2f(s.z); a.w += v * bf2f(s.w);
            }
            acc[rr] = a;
        }

        for (int i = tid; i < ncsz; i += SPT) {
            const int2 v = pairs[nc0 + i];
            stage[i] = v;
            atomicAdd(&cnt[(v.x >> 20) & (KPS - 1)], 1);
        }
        c0 = nc0; csz = ncsz;
        __syncthreads();
    }

    // ---- epilogue -------------------------------------------------------
    const int r0 = sup * KPS + g * 4;
    if (!LN) {
#pragma unroll
        for (int rr = 0; rr < 4; ++rr) {
            const int row = r0 + rr;
            if (row < N_TOTAL) {
                ushort4 o;
                o.x = f2bf(acc[rr].x); o.y = f2bf(acc[rr].y);
                o.z = f2bf(acc[rr].z); o.w = f2bf(acc[rr].w);
                ((ushort4*)dstb)[(size_t)row * 16 + l] = o;
            }
        }
    } else {
        const float4 gm = ((const float4*)gamma)[l];
        const float4 bt = ((const float4*)beta)[l];
#pragma unroll
        for (int rr = 0; rr < 4; ++rr) {
            const int row = r0 + rr;
            const float4 a = acc[rr];
            float s  = a.x + a.y + a.z + a.w;
            float s2 = a.x * a.x + a.y * a.y + a.z * a.z + a.w * a.w;
#pragma unroll
            for (int m = 1; m <= 8; m <<= 1) {   // reduce across the 16-lane group
                s  += __shfl_xor(s,  m, 64);
                s2 += __shfl_xor(s2, m, 64);
            }
            const float mu  = s * (1.0f / EMB);
            const float var = s2 * (1.0f / EMB) - mu * mu;
            const float inv = rsqrtf(var + LN_EPS);
            if (row < N_TOTAL) {
                const float4 eg = ((const float4*)(ego + (size_t)row * EMB))[l];
                float4 o;
                o.x = (a.x - mu) * inv * gm.x + bt.x + eg.x;
                o.y = (a.y - mu) * inv * gm.y + bt.y + eg.y;
                o.z = (a.z - mu) * inv * gm.z + bt.z + eg.z;
                o.w = (a.w - mu) * inv * gm.w + bt.w + eg.w;
                ((float4*)(dstf + (size_t)row * EMB))[l] = o;
            }
        }
    }
}

// ---------------------------------------------------------------------------
// Fallback (round-1) atomic scatter path, fp32, used only if ws too small.
__global__ void transform_kernel(const float* __restrict__ x,
                                 const float* __restrict__ W,
                                 const float* __restrict__ filt,
                                 const float* __restrict__ par,
                                 float* __restrict__ out, int nrows)
{
    __shared__ float Ws[EMB * EMB];
    const int tid = threadIdx.x;
    for (int i = tid; i < EMB * EMB; i += blockDim.x) Ws[i] = W[i];
    __syncthreads();
    const float c = par[0] * par[1];
    const int lane = tid & 63;
    const int wave = tid >> 6;
    const int r0 = blockIdx.x * 32;
    for (int rr = wave; rr < 32; rr += 4) {
        const int r = r0 + rr;
        if (r >= nrows) break;
        const float xv = x[(size_t)r * EMB + lane];
        float acc = 0.f;
#pragma unroll
        for (int k = 0; k < EMB; ++k) {
            const float xk = __shfl(xv, k, 64);
            acc += xk * Ws[k * EMB + lane];
        }
        out[(size_t)r * EMB + lane] = c * filt[r] * acc + xv;
    }
}

__global__ void spmm_scatter(const int* __restrict__ src_idx,
                             const int* __restrict__ dst_idx,
                             const float* __restrict__ vals,
                             const float* __restrict__ src,
                             float* __restrict__ dst, int nnz)
{
    const long long t = (long long)blockIdx.x * blockDim.x + threadIdx.x;
    const int e = (int)(t >> 4);
    const int l = (int)(t & 15);
    if (e >= nnz) return;
    const int s = src_idx[e];
    const int d = dst_idx[e];
    const float v = vals[e];
    const float4 xv = ((const float4*)(src + (size_t)s * EMB))[l];
    float* dp = dst + (size_t)d * EMB + l * 4;
    atomicAdd(dp + 0, v * xv.x);
    atomicAdd(dp + 1, v * xv.y);
    atomicAdd(dp + 2, v * xv.z);
    atomicAdd(dp + 3, v * xv.w);
}

__global__ void ln_residual(const float* y,
                            const float* __restrict__ ego,
                            const float* __restrict__ gamma,
                            const float* __restrict__ beta,
                            float* out, int nrows)
{
    const int lane = threadIdx.x & 63;
    const int wave = threadIdx.x >> 6;
    const int r = blockIdx.x * 4 + wave;
    if (r >= nrows) return;
    const float v = y[(size_t)r * EMB + lane];
    float s = v, s2 = v * v;
#pragma unroll
    for (int off = 32; off > 0; off >>= 1) {
        s  += __shfl_down(s,  off, 64);
        s2 += __shfl_down(s2, off, 64);
    }
    s  = __shfl(s,  0, 64);
    s2 = __shfl(s2, 0, 64);
    const float mu  = s * (1.0f / EMB);
    const float var = s2 * (1.0f / EMB) - mu * mu;
    const float inv = rsqrtf(var + LN_EPS);
    out[(size_t)r * EMB + lane] =
        (v - mu) * inv * gamma[lane] + beta[lane] + ego[(size_t)r * EMB + lane];
}

extern "C" void kernel_launch(void* const* d_in, const int* in_sizes, int n_in,
                              void* d_out, int out_size, void* d_ws, size_t ws_size,
                              hipStream_t stream)
{
    const float* ego     = (const float*)d_in[0];
    const int*   rows    = (const int*)  d_in[1];
    const int*   cols    = (const int*)  d_in[2];
    const float* vals    = (const float*)d_in[3];
    const float* w_uu    = (const float*)d_in[4];
    const float* filt_uu = (const float*)d_in[5];
    const float* par_uu  = (const float*)d_in[6];
    const float* w_ii    = (const float*)d_in[7];
    const float* filt_ii = (const float*)d_in[8];
    const float* par_ii  = (const float*)d_in[9];
    const float* gamma   = (const float*)d_in[10];
    const float* beta    = (const float*)d_in[11];
    float* out = (float*)d_out;
    const int nnz = in_sizes[1];

    const size_t emb_elems = (size_t)N_TOTAL * EMB;
    const size_t emb_bytes = emb_elems * sizeof(float);
    const size_t bf_bytes  = emb_elems * sizeof(unsigned short);

    // fast path: 2 bf16 tables + TWO pairs arrays + counters (~77.0 MB,
    // equals the bound proven available in the original session)
    const size_t need = 2 * bf_bytes + 2 * (size_t)nnz * sizeof(int2)
                        + (size_t)(6 * (NSUP + 1)) * sizeof(int);

    if (ws_size >= need) {
        // ---- fast path: fused dual build + fused LDS-sort + reg pull -----
        unsigned short* ego2b = (unsigned short*)d_ws;    // 12.8 MB
        unsigned short* hb    = ego2b + emb_elems;        // 12.8 MB
        int2* pairs_c = (int2*)(hb + emb_elems);          // 25.6 MB
        int2* pairs_r = pairs_c + nnz;                    // 25.6 MB
        int*  cnt_c  = (int*)(pairs_r + nnz);
        int*  cnt_r  = cnt_c + NSUP;
        int*  base_c = cnt_r + NSUP;
        int*  cur_c  = base_c + (NSUP + 1);
        int*  base_r = cur_c + NSUP;
        int*  cur_r  = base_r + (NSUP + 1);

        hipMemsetAsync(cnt_c, 0, 2 * NSUP * sizeof(int), stream);

        hist_sup<<<512, 256, 0, stream>>>(rows, cols, cnt_r, cnt_c, nnz);
        scan_sup<<<2, 1024, 0, stream>>>(cnt_c, base_c, cur_c,
                                         cnt_r, base_r, cur_r);

        transform_tile<<<N_TOTAL / TR_ROWS, 256, 0, stream>>>(
            ego, w_uu, filt_uu, par_uu, w_ii, filt_ii, par_ii, ego2b);

        const int l1b = (nnz + EPB - 1) / EPB;
        build_both<<<l1b, BLT, 0, stream>>>(rows, cols, vals,
                                            cur_c, pairs_c, cur_r, pairs_r, nnz);

        // Pass 1: key = col, payload = row.  h[c] = sum val*ego2[r]  (bf16)
        spmm_fused<false><<<NSUP, SPT, 0, stream>>>(
            base_c, pairs_c, ego2b, nullptr, nullptr, nullptr, hb, nullptr);

        // Pass 2: key = row, payload = col.  out = LN(A h) + ego, fused.
        spmm_fused<true><<<NSUP, SPT, 0, stream>>>(
            base_r, pairs_r, hb, ego, gamma, beta, nullptr, out);
    } else {
        // ---------------- fallback: atomic scatter (round-1, fp32) -------
        float* ego2 = (float*)d_ws;
        float* h    = ego2 + emb_elems;
        hipMemsetAsync(h,   0, emb_bytes, stream);
        hipMemsetAsync(out, 0, emb_bytes, stream);

        transform_kernel<<<(N_USERS + 31) / 32, 256, 0, stream>>>(
            ego, w_uu, filt_uu, par_uu, ego2, N_USERS);
        transform_kernel<<<(N_ITEMS + 31) / 32, 256, 0, stream>>>(
            ego + (size_t)N_USERS * EMB, w_ii, filt_ii, par_ii,
            ego2 + (size_t)N_USERS * EMB, N_ITEMS);

        const long long thr = (long long)nnz * 16;
        const int sblocks = (int)((thr + 255) / 256);
        spmm_scatter<<<sblocks, 256, 0, stream>>>(rows, cols, vals, ego2, h, nnz);
        spmm_scatter<<<sblocks, 256, 0, stream>>>(cols, rows, vals, h, out, nnz);

        const int rb = (N_TOTAL + 3) / 4;
        ln_residual<<<rb, 256, 0, stream>>>(out, ego, gamma, beta, out, N_TOTAL);
    }
}

// Round 9
// 434.524 us; speedup vs baseline: 1.0426x; 1.0426x over previous
//
#include <hip/hip_runtime.h>

#define N_USERS 60000
#define N_ITEMS 40000
#define N_TOTAL 100000
#define EMB 64
#define LN_EPS 1e-5f

// Build granularity: 512-row super-buckets (big, coalesced bursts).
#define SUPSH 9                                  // log2(512)
#define NSUPB ((N_TOTAL + 511) / 512)            // 196
// SpMM granularity: 128-row quarters of a build sup.
#define KPS 128                                  // keys per spmm block
#define EPB 4096                                 // edges per build block
#define BLT 512                                  // build threads (8 waves)
#define EPT (EPB / BLT)                          // 8 edges per thread
#define TR_ROWS 32                               // rows per transform block
#define XPITCH 68                                // x-tile pitch (floats)
#define RD 2048                                  // spmm read chunk (per flush)
#define CAP 2048                                 // spmm stage capacity (>= RD: no overflow)
#define SPT 512                                  // spmm threads (8 waves)
#define SUPX 25                                  // sups per XCD (8*25=200 >= 196)

// bf16 helpers (exact shift for bf16->f32; RNE for f32->bf16)
__device__ __forceinline__ float bf2f(unsigned short h)
{ return __uint_as_float(((unsigned)h) << 16); }
__device__ __forceinline__ unsigned short f2bf(float f)
{
    unsigned u = __float_as_uint(f);
    return (unsigned short)((u + 0x7FFFu + ((u >> 16) & 1u)) >> 16);
}

// ---------------------------------------------------------------------------
// ego2[r,:] = c * filt[r] * (x[r,:] @ W) + x[r,:]   (bf16 output)
__global__ void transform_tile(const float* __restrict__ x,
                               const float* __restrict__ w_uu,
                               const float* __restrict__ filt_uu,
                               const float* __restrict__ par_uu,
                               const float* __restrict__ w_ii,
                               const float* __restrict__ filt_ii,
                               const float* __restrict__ par_ii,
                               unsigned short* __restrict__ out)
{
    __shared__ float Wls[EMB * EMB];             // 16 KB
    __shared__ float xs[TR_ROWS * XPITCH];       // 8.7 KB
    const int tid = threadIdx.x;
    const int r0 = blockIdx.x * TR_ROWS;
    const int itm = (r0 >= N_USERS);             // uniform per block
    const float* W  = itm ? w_ii : w_uu;
    const float* fb = itm ? filt_ii : filt_uu;
    const int foff  = itm ? N_USERS : 0;
    const float c   = itm ? par_ii[0] * par_ii[1] : par_uu[0] * par_uu[1];

    for (int i = tid; i < EMB * EMB / 4; i += 256)
        ((float4*)Wls)[i] = ((const float4*)W)[i];
    for (int i = tid; i < TR_ROWS * 16; i += 256) {
        const float4 v = ((const float4*)x)[r0 * 16 + i];
        *(float4*)&xs[(i >> 4) * XPITCH + (i & 15) * 4] = v;
    }
    __syncthreads();

    const int lane = tid & 63;
    const int wv = tid >> 6;
    const int rg = lane >> 4;
    const int j  = lane & 15;

#pragma unroll
    for (int it = 0; it < 2; ++it) {
        const int rl = wv * 8 + it * 4 + rg;
        const int row = r0 + rl;
        float4 acc = make_float4(0.f, 0.f, 0.f, 0.f);
#pragma unroll 8
        for (int k = 0; k < EMB; ++k) {
            const float xb = xs[rl * XPITCH + k];
            const float4 w4 = *(const float4*)&Wls[k * EMB + 4 * j];
            acc.x += xb * w4.x; acc.y += xb * w4.y;
            acc.z += xb * w4.z; acc.w += xb * w4.w;
        }
        const float cf = c * fb[row - foff];
        const float4 xv = *(const float4*)&xs[rl * XPITCH + 4 * j];
        ushort4 o;
        o.x = f2bf(cf * acc.x + xv.x);
        o.y = f2bf(cf * acc.y + xv.y);
        o.z = f2bf(cf * acc.z + xv.z);
        o.w = f2bf(cf * acc.w + xv.w);
        *(ushort4*)&out[(size_t)row * EMB + 4 * j] = o;
    }
}

// ---------------------------------------------------------------------------
// 196-bucket histograms for BOTH orderings, int4-vectorized input loads.
__global__ void hist_sup(const int* __restrict__ rows,
                         const int* __restrict__ cols,
                         int* __restrict__ cnt_r,
                         int* __restrict__ cnt_c, int nnz)
{
    __shared__ int hr[NSUPB], hc[NSUPB];
    const int tid = threadIdx.x;
    for (int i = tid; i < NSUPB; i += 256) { hr[i] = 0; hc[i] = 0; }
    __syncthreads();
    const int nq = nnz >> 2;
    for (int q = blockIdx.x * 256 + tid; q < nq; q += gridDim.x * 256) {
        const int4 r4 = ((const int4*)rows)[q];
        const int4 c4 = ((const int4*)cols)[q];
        atomicAdd(&hr[r4.x >> SUPSH], 1); atomicAdd(&hc[c4.x >> SUPSH], 1);
        atomicAdd(&hr[r4.y >> SUPSH], 1); atomicAdd(&hc[c4.y >> SUPSH], 1);
        atomicAdd(&hr[r4.z >> SUPSH], 1); atomicAdd(&hc[c4.z >> SUPSH], 1);
        atomicAdd(&hr[r4.w >> SUPSH], 1); atomicAdd(&hc[c4.w >> SUPSH], 1);
    }
    for (int e = (nq << 2) + blockIdx.x * 256 + tid; e < nnz; e += gridDim.x * 256) {
        atomicAdd(&hr[rows[e] >> SUPSH], 1);
        atomicAdd(&hc[cols[e] >> SUPSH], 1);
    }
    __syncthreads();
    for (int i = tid; i < NSUPB; i += 256) {
        if (hr[i]) atomicAdd(&cnt_r[i], hr[i]);
        if (hc[i]) atomicAdd(&cnt_c[i], hc[i]);
    }
}

// Exclusive scan of the NSUPB counters. grid=2: blk0=cols, 1=rows.
__global__ void scan_sup(const int* __restrict__ cnt_c, int* __restrict__ base_c,
                         int* __restrict__ cur_c,
                         const int* __restrict__ cnt_r, int* __restrict__ base_r,
                         int* __restrict__ cur_r)
{
    const int* cnt = blockIdx.x ? cnt_r : cnt_c;
    int* base = blockIdx.x ? base_r : base_c;
    int* cur  = blockIdx.x ? cur_r  : cur_c;
    __shared__ int wsum[16];
    const int i = threadIdx.x;                   // 1024 threads = 16 waves
    const int lane = i & 63;
    const int wv = i >> 6;
    const int v = (i < NSUPB) ? cnt[i] : 0;
    int incl = v;
#pragma unroll
    for (int off = 1; off < 64; off <<= 1) {
        const int t = __shfl_up(incl, off, 64);
        if (lane >= off) incl += t;
    }
    if (lane == 63) wsum[wv] = incl;
    __syncthreads();
    if (i == 0) {
        int run = 0;
#pragma unroll
        for (int w = 0; w < 16; ++w) { const int t = wsum[w]; wsum[w] = run; run += t; }
        base[NSUPB] = run;
    }
    __syncthreads();
    const int excl = wsum[wv] + incl - v;
    if (i < NSUPB) { base[i] = excl; cur[i] = excl; }
}

// ---------------------------------------------------------------------------
// Fused dual-ordering grouping at 196-bucket granularity.
// Round-7 lesson: emit time is TRANSACTION-bound on burst size
// (f(5.2 edges)=53.5, f(2.6)=120 in the time~f(burst)/occ model). At 196
// buckets: bursts = 4096/196 ~ 21 edges = 167 B (coalesced), LDS 39 KB ->
// 4 blocks/CU = 32 waves/CU. Both axes improve at once.
// Payload: other(17b) | (key & 511) << 20.
__global__ void __launch_bounds__(BLT, 6)
build_both(const int* __restrict__ rows,
           const int* __restrict__ cols,
           const float* __restrict__ vals,
           int* __restrict__ cur_c, int2* __restrict__ pairs_c,
           int* __restrict__ cur_r, int2* __restrict__ pairs_r, int nnz)
{
    __shared__ int2 stage[EPB];                  // 32 KB
    __shared__ unsigned char sg[EPB];            // 4 KB (196 < 256)
    __shared__ int hist_c[NSUPB];
    __shared__ int hist_r[NSUPB];
    __shared__ int goff[NSUPB];                  // gbase - sexcl (per pass)
    __shared__ int lcur[NSUPB];                  // running sexcl (per pass)
    __shared__ int wsum[8];

    const int tid = threadIdx.x;
    const int e0 = blockIdx.x * EPB;
    const int ecnt = min(EPB, nnz - e0);

    for (int i = tid; i < NSUPB; i += BLT) { hist_c[i] = 0; hist_r[i] = 0; }
    __syncthreads();

    int myr[EPT], myc[EPT];
    float myv[EPT];
#pragma unroll
    for (int i = 0; i < EPT; ++i) {
        const int s = tid + i * BLT;
        if (s < ecnt) {
            const int e = e0 + s;
            myr[i] = rows[e]; myc[i] = cols[e]; myv[i] = vals[e];
            atomicAdd(&hist_c[myc[i] >> SUPSH], 1);  // independent chains
            atomicAdd(&hist_r[myr[i] >> SUPSH], 1);
        } else myr[i] = -1;
    }
    __syncthreads();

    // ---- two passes: p=0 keyed by col -> pairs_c, p=1 keyed by row -------
#pragma unroll 1
    for (int p = 0; p < 2; ++p) {
        const int* hist = p ? hist_r : hist_c;
        int* gcur = p ? cur_r  : cur_c;
        int2* out = p ? pairs_r : pairs_c;

        // exclusive scan of hist[0..NSUPB): thread t owns entries 2t, 2t+1
        {
            const int lane = tid & 63;
            const int wv = tid >> 6;             // 0..7
            const int i0 = tid * 2;
            const int va = (i0     < NSUPB) ? hist[i0]     : 0;
            const int vb = (i0 + 1 < NSUPB) ? hist[i0 + 1] : 0;
            const int tsum = va + vb;
            int incl = tsum;
#pragma unroll
            for (int off = 1; off < 64; off <<= 1) {
                const int t = __shfl_up(incl, off, 64);
                if (lane >= off) incl += t;
            }
            if (lane == 63) wsum[wv] = incl;
            __syncthreads();
            int woff = 0;
            for (int w = 0; w < wv; ++w) woff += wsum[w];
            const int excl = woff + incl - tsum;
            if (i0 < NSUPB) {
                const int gb = va ? atomicAdd(&gcur[i0], va) : 0;
                lcur[i0] = excl;
                goff[i0] = gb - excl;
            }
            if (i0 + 1 < NSUPB) {
                const int gb = vb ? atomicAdd(&gcur[i0 + 1], vb) : 0;
                lcur[i0 + 1] = excl + va;
                goff[i0 + 1] = gb - (excl + va);
            }
        }
        __syncthreads();

        // scatter into stage, grouped by this ordering's super-bucket
#pragma unroll
        for (int i = 0; i < EPT; ++i) {
            if (myr[i] >= 0) {
                const int key   = p ? myr[i] : myc[i];
                const int other = p ? myc[i] : myr[i];
                const int g = key >> SUPSH;
                const int s = atomicAdd(&lcur[g], 1);
                stage[s] = make_int2(other | ((key & 511) << 20),
                                     __float_as_int(myv[i]));
                sg[s] = (unsigned char)g;
            }
        }
        __syncthreads();

        // emit grouped bursts (~21 edges each): one indexed LDS read per edge
        for (int s = tid; s < ecnt; s += BLT)
            out[goff[sg[s]] + s] = stage[s];
        __syncthreads();                         // stage/goff/lcur reuse
    }
}

// ---------------------------------------------------------------------------
// SpMM over quarter-filtered 512-row regions. Grid = 800 (8 XCD x 25 sups x
// 4 quarters, 16 pad blocks idle). XCD-bijective mapping puts the 4 quarter
// blocks of one sup on ONE XCD so the 4x region re-read hits that XCD's L2.
// Per 2048-edge chunk: stream+filter (match <= chunk <= CAP: no overflow) ->
// 128-key LDS counting sort -> per-group register pull (16-lane group owns
// 4 rows; acc persists across chunks). 3 barriers/chunk.
// (Round-2 lesson: no LDS FP atomics. Round-7 lesson: build bursts must be
//  big, so the fine 128-row grouping moved here, where it's an LDS sort.)
template <bool LN>
__global__ void __launch_bounds__(SPT, 6)
spmm_fused(const int* __restrict__ base,
           const int2* __restrict__ pairs,
           const unsigned short* __restrict__ src,
           const float* __restrict__ ego,
           const float* __restrict__ gamma,
           const float* __restrict__ beta,
           unsigned short* __restrict__ dstb,
           float* __restrict__ dstf)
{
    __shared__ int2 stage[CAP];                  // 16 KB
    __shared__ int2 sorted[CAP];                 // 16 KB
    __shared__ int cnt[KPS];                     // 512 B
    __shared__ int kbase[KPS];                   // 512 B
    __shared__ int kcur[KPS];                    // 512 B
    __shared__ int scnt;

    const int phys = blockIdx.x;
    const int xcd = phys & 7;
    const int jj  = phys >> 3;                   // 0..99
    const int sup = xcd * SUPX + (jj >> 2);
    const int q   = jj & 3;
    if (sup >= NSUPB) return;                    // pad blocks (uniform)

    const int tid = threadIdx.x;
    const int beg = base[sup];
    const int end = base[sup + 1];
    const int g = tid >> 4;                      // 32 groups of 16 lanes
    const int l = tid & 15;

    float4 acc[4];
#pragma unroll
    for (int i = 0; i < 4; ++i) acc[i] = make_float4(0.f, 0.f, 0.f, 0.f);

    if (tid < KPS) cnt[tid] = 0;
    if (tid == 0) scnt = 0;
    __syncthreads();

    for (int c0 = beg; c0 < end; c0 += RD) {
        const int csz = min(RD, end - c0);

        // ---- stream + filter to this quarter ----------------------------
#pragma unroll
        for (int u = 0; u < RD / SPT; ++u) {
            const int i = tid + u * SPT;
            if (i < csz) {
                const int2 p = pairs[c0 + i];
                const int key9 = (p.x >> 20) & 511;
                if ((key9 >> 7) == q) {
                    const int pos = atomicAdd(&scnt, 1);
                    stage[pos] = p;
                    atomicAdd(&cnt[key9 & (KPS - 1)], 1);
                }
            }
        }
        __syncthreads();                         // A: appends done
        const int S = scnt;

        // ---- scan of 128 counters by wave 0 (lane owns 2 keys) -----------
        if (tid < 64) {
            const int ca = cnt[tid * 2];
            const int cb = cnt[tid * 2 + 1];
            const int tsum = ca + cb;
            int incl = tsum;
#pragma unroll
            for (int off = 1; off < 64; off <<= 1) {
                const int t = __shfl_up(incl, off, 64);
                if (tid >= off) incl += t;
            }
            const int run = incl - tsum;
            kbase[tid * 2] = run;          kcur[tid * 2] = run;
            kbase[tid * 2 + 1] = run + ca; kcur[tid * 2 + 1] = run + ca;
            cnt[tid * 2] = 0; cnt[tid * 2 + 1] = 0;   // ready for next chunk
        }
        __syncthreads();                         // B: all read S; kbase ready
        if (tid == 0) scnt = 0;                  // safe: S already latched

        // ---- counting-sort scatter (int LDS atomics) ---------------------
        for (int i = tid; i < S; i += SPT) {
            const int2 v = stage[i];
            const int pos = atomicAdd(&kcur[(v.x >> 20) & (KPS - 1)], 1);
            sorted[pos] = v;
        }
        __syncthreads();                         // C: sorted ready

        // ---- consume: 4/1 ladder (runs avg ~4 per row per chunk) ---------
#pragma unroll
        for (int rr = 0; rr < 4; ++rr) {
            const int k = g * 4 + rr;
            int j = kbase[k];
            const int e = kcur[k];               // == end of key's run
            float4 a = acc[rr];
            for (; j + 4 <= e; j += 4) {
                int2 p[4]; ushort4 s[4];
#pragma unroll
                for (int u = 0; u < 4; ++u) p[u] = sorted[j + u];
#pragma unroll
                for (int u = 0; u < 4; ++u)
                    s[u] = ((const ushort4*)(src + (size_t)(p[u].x & 0x1FFFF) * EMB))[l];
#pragma unroll
                for (int u = 0; u < 4; ++u) {
                    const float v = __int_as_float(p[u].y);
                    a.x += v * bf2f(s[u].x); a.y += v * bf2f(s[u].y);
                    a.z += v * bf2f(s[u].z); a.w += v * bf2f(s[u].w);
                }
            }
            for (; j < e; ++j) {
                const int2 p = sorted[j];
                const ushort4 s = ((const ushort4*)(src + (size_t)(p.x & 0x1FFFF) * EMB))[l];
                const float v = __int_as_float(p.y);
                a.x += v * bf2f(s.x); a.y += v * bf2f(s.y);
                a.z += v * bf2f(s.z); a.w += v * bf2f(s.w);
            }
            acc[rr] = a;
        }
        // no barrier: next append writes stage/cnt/scnt, consume reads
        // sorted/kbase/kcur — disjoint; bar A orders the next scan.
    }

    // ---- epilogue -------------------------------------------------------
    const int r0 = sup * 512 + q * KPS + g * 4;
    if (!LN) {
#pragma unroll
        for (int rr = 0; rr < 4; ++rr) {
            const int row = r0 + rr;
            if (row < N_TOTAL) {
                ushort4 o;
                o.x = f2bf(acc[rr].x); o.y = f2bf(acc[rr].y);
                o.z = f2bf(acc[rr].z); o.w = f2bf(acc[rr].w);
                ((ushort4*)dstb)[(size_t)row * 16 + l] = o;
            }
        }
    } else {
        const float4 gm = ((const float4*)gamma)[l];
        const float4 bt = ((const float4*)beta)[l];
#pragma unroll
        for (int rr = 0; rr < 4; ++rr) {
            const int row = r0 + rr;
            const float4 a = acc[rr];
            float s  = a.x + a.y + a.z + a.w;
            float s2 = a.x * a.x + a.y * a.y + a.z * a.z + a.w * a.w;
#pragma unroll
            for (int m = 1; m <= 8; m <<= 1) {   // reduce across the 16-lane group
                s  += __shfl_xor(s,  m, 64);
                s2 += __shfl_xor(s2, m, 64);
            }
            const float mu  = s * (1.0f / EMB);
            const float var = s2 * (1.0f / EMB) - mu * mu;
            const float inv = rsqrtf(var + LN_EPS);
            if (row < N_TOTAL) {
                const float4 eg = ((const float4*)(ego + (size_t)row * EMB))[l];
                float4 o;
                o.x = (a.x - mu) * inv * gm.x + bt.x + eg.x;
                o.y = (a.y - mu) * inv * gm.y + bt.y + eg.y;
                o.z = (a.z - mu) * inv * gm.z + bt.z + eg.z;
                o.w = (a.w - mu) * inv * gm.w + bt.w + eg.w;
                ((float4*)(dstf + (size_t)row * EMB))[l] = o;
            }
        }
    }
}

// ---------------------------------------------------------------------------
// Fallback (round-1) atomic scatter path, fp32, used only if ws too small.
__global__ void transform_kernel(const float* __restrict__ x,
                                 const float* __restrict__ W,
                                 const float* __restrict__ filt,
                                 const float* __restrict__ par,
                                 float* __restrict__ out, int nrows)
{
    __shared__ float Ws[EMB * EMB];
    const int tid = threadIdx.x;
    for (int i = tid; i < EMB * EMB; i += blockDim.x) Ws[i] = W[i];
    __syncthreads();
    const float c = par[0] * par[1];
    const int lane = tid & 63;
    const int wave = tid >> 6;
    const int r0 = blockIdx.x * 32;
    for (int rr = wave; rr < 32; rr += 4) {
        const int r = r0 + rr;
        if (r >= nrows) break;
        const float xv = x[(size_t)r * EMB + lane];
        float acc = 0.f;
#pragma unroll
        for (int k = 0; k < EMB; ++k) {
            const float xk = __shfl(xv, k, 64);
            acc += xk * Ws[k * EMB + lane];
        }
        out[(size_t)r * EMB + lane] = c * filt[r] * acc + xv;
    }
}

__global__ void spmm_scatter(const int* __restrict__ src_idx,
                             const int* __restrict__ dst_idx,
                             const float* __restrict__ vals,
                             const float* __restrict__ src,
                             float* __restrict__ dst, int nnz)
{
    const long long t = (long long)blockIdx.x * blockDim.x + threadIdx.x;
    const int e = (int)(t >> 4);
    const int l = (int)(t & 15);
    if (e >= nnz) return;
    const int s = src_idx[e];
    const int d = dst_idx[e];
    const float v = vals[e];
    const float4 xv = ((const float4*)(src + (size_t)s * EMB))[l];
    float* dp = dst + (size_t)d * EMB + l * 4;
    atomicAdd(dp + 0, v * xv.x);
    atomicAdd(dp + 1, v * xv.y);
    atomicAdd(dp + 2, v * xv.z);
    atomicAdd(dp + 3, v * xv.w);
}

__global__ void ln_residual(const float* y,
                            const float* __restrict__ ego,
                            const float* __restrict__ gamma,
                            const float* __restrict__ beta,
                            float* out, int nrows)
{
    const int lane = threadIdx.x & 63;
    const int wave = threadIdx.x >> 6;
    const int r = blockIdx.x * 4 + wave;
    if (r >= nrows) return;
    const float v = y[(size_t)r * EMB + lane];
    float s = v, s2 = v * v;
#pragma unroll
    for (int off = 32; off > 0; off >>= 1) {
        s  += __shfl_down(s,  off, 64);
        s2 += __shfl_down(s2, off, 64);
    }
    s  = __shfl(s,  0, 64);
    s2 = __shfl(s2, 0, 64);
    const float mu  = s * (1.0f / EMB);
    const float var = s2 * (1.0f / EMB) - mu * mu;
    const float inv = rsqrtf(var + LN_EPS);
    out[(size_t)r * EMB + lane] =
        (v - mu) * inv * gamma[lane] + beta[lane] + ego[(size_t)r * EMB + lane];
}

extern "C" void kernel_launch(void* const* d_in, const int* in_sizes, int n_in,
                              void* d_out, int out_size, void* d_ws, size_t ws_size,
                              hipStream_t stream)
{
    const float* ego     = (const float*)d_in[0];
    const int*   rows    = (const int*)  d_in[1];
    const int*   cols    = (const int*)  d_in[2];
    const float* vals    = (const float*)d_in[3];
    const float* w_uu    = (const float*)d_in[4];
    const float* filt_uu = (const float*)d_in[5];
    const float* par_uu  = (const float*)d_in[6];
    const float* w_ii    = (const float*)d_in[7];
    const float* filt_ii = (const float*)d_in[8];
    const float* par_ii  = (const float*)d_in[9];
    const float* gamma   = (const float*)d_in[10];
    const float* beta    = (const float*)d_in[11];
    float* out = (float*)d_out;
    const int nnz = in_sizes[1];

    const size_t emb_elems = (size_t)N_TOTAL * EMB;
    const size_t emb_bytes = emb_elems * sizeof(float);
    const size_t bf_bytes  = emb_elems * sizeof(unsigned short);

    // fast path: 2 bf16 tables + TWO pairs arrays + counters (~77.0 MB,
    // equals the bound proven available in earlier rounds)
    const size_t need = 2 * bf_bytes + 2 * (size_t)nnz * sizeof(int2)
                        + (size_t)(6 * (NSUPB + 1)) * sizeof(int);

    if (ws_size >= need) {
        // ---- fast path: coarse dual build + filtered LDS-sort + reg pull -
        unsigned short* ego2b = (unsigned short*)d_ws;    // 12.8 MB
        unsigned short* hb    = ego2b + emb_elems;        // 12.8 MB
        int2* pairs_c = (int2*)(hb + emb_elems);          // 25.6 MB
        int2* pairs_r = pairs_c + nnz;                    // 25.6 MB
        int*  cnt_c  = (int*)(pairs_r + nnz);
        int*  cnt_r  = cnt_c + NSUPB;
        int*  base_c = cnt_r + NSUPB;
        int*  cur_c  = base_c + (NSUPB + 1);
        int*  base_r = cur_c + NSUPB;
        int*  cur_r  = base_r + (NSUPB + 1);

        hipMemsetAsync(cnt_c, 0, 2 * NSUPB * sizeof(int), stream);

        hist_sup<<<512, 256, 0, stream>>>(rows, cols, cnt_r, cnt_c, nnz);
        scan_sup<<<2, 1024, 0, stream>>>(cnt_c, base_c, cur_c,
                                         cnt_r, base_r, cur_r);

        transform_tile<<<N_TOTAL / TR_ROWS, 256, 0, stream>>>(
            ego, w_uu, filt_uu, par_uu, w_ii, filt_ii, par_ii, ego2b);

        const int l1b = (nnz + EPB - 1) / EPB;
        build_both<<<l1b, BLT, 0, stream>>>(rows, cols, vals,
                                            cur_c, pairs_c, cur_r, pairs_r, nnz);

        // Pass 1: key = col, payload = row.  h[c] = sum val*ego2[r]  (bf16)
        spmm_fused<false><<<8 * SUPX * 4, SPT, 0, stream>>>(
            base_c, pairs_c, ego2b, nullptr, nullptr, nullptr, hb, nullptr);

        // Pass 2: key = row, payload = col.  out = LN(A h) + ego, fused.
        spmm_fused<true><<<8 * SUPX * 4, SPT, 0, stream>>>(
            base_r, pairs_r, hb, ego, gamma, beta, nullptr, out);
    } else {
        // ---------------- fallback: atomic scatter (round-1, fp32) -------
        float* ego2 = (float*)d_ws;
        float* h    = ego2 + emb_elems;
        hipMemsetAsync(h,   0, emb_bytes, stream);
        hipMemsetAsync(out, 0, emb_bytes, stream);

        transform_kernel<<<(N_USERS + 31) / 32, 256, 0, stream>>>(
            ego, w_uu, filt_uu, par_uu, ego2, N_USERS);
        transform_kernel<<<(N_ITEMS + 31) / 32, 256, 0, stream>>>(
            ego + (size_t)N_USERS * EMB, w_ii, filt_ii, par_ii,
            ego2 + (size_t)N_USERS * EMB, N_ITEMS);

        const long long thr = (long long)nnz * 16;
        const int sblocks = (int)((thr + 255) / 256);
        spmm_scatter<<<sblocks, 256, 0, stream>>>(rows, cols, vals, ego2, h, nnz);
        spmm_scatter<<<sblocks, 256, 0, stream>>>(cols, rows, vals, h, out, nnz);

        const int rb = (N_TOTAL + 3) / 4;
        ln_residual<<<rb, 256, 0, stream>>>(out, ego, gamma, beta, out, N_TOTAL);
    }
}

// Round 10
// 360.479 us; speedup vs baseline: 1.2567x; 1.2054x over previous
//
#include <hip/hip_runtime.h>

#define N_USERS 60000
#define N_ITEMS 40000
#define N_TOTAL 100000
#define EMB 64
#define LN_EPS 1e-5f

#define KPS 128                                  // keys (dest rows) per bucket
#define KSH 7                                    // log2(KPS)
#define NSUP ((N_TOTAL + KPS - 1) / KPS)         // 782
#define EPB 8192                                 // edges per build block (391 blocks)
#define BLT 1024                                 // build threads (16 waves)
#define EPT (EPB / BLT)                          // 8 edges per thread
#define TR_ROWS 32                               // rows per transform block
#define XPITCH 68                                // x-tile pitch (floats)
#define CAP 2048                                 // spmm LDS sort chunk
#define SPT 512                                  // spmm threads (8 waves)

// bf16 helpers (exact shift for bf16->f32; RNE for f32->bf16)
__device__ __forceinline__ float bf2f(unsigned short h)
{ return __uint_as_float(((unsigned)h) << 16); }
__device__ __forceinline__ unsigned short f2bf(float f)
{
    unsigned u = __float_as_uint(f);
    return (unsigned short)((u + 0x7FFFu + ((u >> 16) & 1u)) >> 16);
}

// ---------------------------------------------------------------------------
// ego2[r,:] = c * filt[r] * (x[r,:] @ W) + x[r,:]   (bf16 output)
__global__ void transform_tile(const float* __restrict__ x,
                               const float* __restrict__ w_uu,
                               const float* __restrict__ filt_uu,
                               const float* __restrict__ par_uu,
                               const float* __restrict__ w_ii,
                               const float* __restrict__ filt_ii,
                               const float* __restrict__ par_ii,
                               unsigned short* __restrict__ out)
{
    __shared__ float Wls[EMB * EMB];             // 16 KB
    __shared__ float xs[TR_ROWS * XPITCH];       // 8.7 KB
    const int tid = threadIdx.x;
    const int r0 = blockIdx.x * TR_ROWS;
    const int itm = (r0 >= N_USERS);             // uniform per block
    const float* W  = itm ? w_ii : w_uu;
    const float* fb = itm ? filt_ii : filt_uu;
    const int foff  = itm ? N_USERS : 0;
    const float c   = itm ? par_ii[0] * par_ii[1] : par_uu[0] * par_uu[1];

    for (int i = tid; i < EMB * EMB / 4; i += 256)
        ((float4*)Wls)[i] = ((const float4*)W)[i];
    for (int i = tid; i < TR_ROWS * 16; i += 256) {
        const float4 v = ((const float4*)x)[r0 * 16 + i];
        *(float4*)&xs[(i >> 4) * XPITCH + (i & 15) * 4] = v;
    }
    __syncthreads();

    const int lane = tid & 63;
    const int wv = tid >> 6;
    const int rg = lane >> 4;
    const int j  = lane & 15;

#pragma unroll
    for (int it = 0; it < 2; ++it) {
        const int rl = wv * 8 + it * 4 + rg;
        const int row = r0 + rl;
        float4 acc = make_float4(0.f, 0.f, 0.f, 0.f);
#pragma unroll 8
        for (int k = 0; k < EMB; ++k) {
            const float xb = xs[rl * XPITCH + k];
            const float4 w4 = *(const float4*)&Wls[k * EMB + 4 * j];
            acc.x += xb * w4.x; acc.y += xb * w4.y;
            acc.z += xb * w4.z; acc.w += xb * w4.w;
        }
        const float cf = c * fb[row - foff];
        const float4 xv = *(const float4*)&xs[rl * XPITCH + 4 * j];
        ushort4 o;
        o.x = f2bf(cf * acc.x + xv.x);
        o.y = f2bf(cf * acc.y + xv.y);
        o.z = f2bf(cf * acc.z + xv.z);
        o.w = f2bf(cf * acc.w + xv.w);
        *(ushort4*)&out[(size_t)row * EMB + 4 * j] = o;
    }
}

// ---------------------------------------------------------------------------
// 782-bucket histograms for BOTH orderings, int4-vectorized input loads.
__global__ void hist_sup(const int* __restrict__ rows,
                         const int* __restrict__ cols,
                         int* __restrict__ cnt_r,
                         int* __restrict__ cnt_c, int nnz)
{
    __shared__ int hr[NSUP], hc[NSUP];
    const int tid = threadIdx.x;
    for (int i = tid; i < NSUP; i += 256) { hr[i] = 0; hc[i] = 0; }
    __syncthreads();
    const int nq = nnz >> 2;
    for (int q = blockIdx.x * 256 + tid; q < nq; q += gridDim.x * 256) {
        const int4 r4 = ((const int4*)rows)[q];
        const int4 c4 = ((const int4*)cols)[q];
        atomicAdd(&hr[r4.x >> KSH], 1); atomicAdd(&hc[c4.x >> KSH], 1);
        atomicAdd(&hr[r4.y >> KSH], 1); atomicAdd(&hc[c4.y >> KSH], 1);
        atomicAdd(&hr[r4.z >> KSH], 1); atomicAdd(&hc[c4.z >> KSH], 1);
        atomicAdd(&hr[r4.w >> KSH], 1); atomicAdd(&hc[c4.w >> KSH], 1);
    }
    for (int e = (nq << 2) + blockIdx.x * 256 + tid; e < nnz; e += gridDim.x * 256) {
        atomicAdd(&hr[rows[e] >> KSH], 1);
        atomicAdd(&hc[cols[e] >> KSH], 1);
    }
    __syncthreads();
    for (int i = tid; i < NSUP; i += 256) {
        if (hr[i]) atomicAdd(&cnt_r[i], hr[i]);
        if (hc[i]) atomicAdd(&cnt_c[i], hc[i]);
    }
}

// Exclusive scan of the NSUP counters (NSUP <= 1024). grid=2: blk0=cols, 1=rows.
__global__ void scan_sup(const int* __restrict__ cnt_c, int* __restrict__ base_c,
                         int* __restrict__ cur_c,
                         const int* __restrict__ cnt_r, int* __restrict__ base_r,
                         int* __restrict__ cur_r)
{
    const int* cnt = blockIdx.x ? cnt_r : cnt_c;
    int* base = blockIdx.x ? base_r : base_c;
    int* cur  = blockIdx.x ? cur_r  : cur_c;
    __shared__ int wsum[16];
    const int i = threadIdx.x;                   // 1024 threads = 16 waves
    const int lane = i & 63;
    const int wv = i >> 6;
    const int v = (i < NSUP) ? cnt[i] : 0;
    int incl = v;
#pragma unroll
    for (int off = 1; off < 64; off <<= 1) {
        const int t = __shfl_up(incl, off, 64);
        if (lane >= off) incl += t;
    }
    if (lane == 63) wsum[wv] = incl;
    __syncthreads();
    if (i == 0) {
        int run = 0;
#pragma unroll
        for (int w = 0; w < 16; ++w) { const int t = wsum[w]; wsum[w] = run; run += t; }
        base[NSUP] = run;
    }
    __syncthreads();
    const int excl = wsum[wv] + incl - v;
    if (i < NSUP) { base[i] = excl; cur[i] = excl; }
}

// ---------------------------------------------------------------------------
// STAGE-FREE dual-ordering build: direct global scatter.
// Round-9 lesson: the LDS stage + emit phases don't pay — the line-level
// write footprint is ~2x ideal either way (r6 WRITE=48.6 MB), and burst
// coarsening (196 buckets) just trades into 4x-longer per-cursor atomic
// chains (no net gain). So: per edge = 1 LDS hist atomic + 1 LDS lcur
// atomic + 1 direct global 8B store (L2 write-combines same-line stores).
// 3 phases, no scans, ~10 KB LDS. EPB=8192/BLT=1024 -> 391 blocks halves
// per-cursor chains (~390/address).
// Payload: other(17b) | (key & 127) << 20.
__global__ void __launch_bounds__(BLT, 2)
build_both(const int* __restrict__ rows,
           const int* __restrict__ cols,
           const float* __restrict__ vals,
           int* __restrict__ cur_c, int2* __restrict__ pairs_c,
           int* __restrict__ cur_r, int2* __restrict__ pairs_r, int nnz)
{
    __shared__ int hist_c[NSUP];                 // 3.1 KB
    __shared__ int hist_r[NSUP];                 // 3.1 KB
    __shared__ int lcur[NSUP];                   // 3.1 KB (reused per pass)

    const int tid = threadIdx.x;
    const int e0 = blockIdx.x * EPB;
    const int ecnt = min(EPB, nnz - e0);

    for (int i = tid; i < NSUP; i += BLT) { hist_c[i] = 0; hist_r[i] = 0; }
    __syncthreads();

    int myr[EPT], myc[EPT];
    float myv[EPT];
#pragma unroll
    for (int i = 0; i < EPT; ++i) {
        const int s = tid + i * BLT;
        if (s < ecnt) {
            const int e = e0 + s;
            myr[i] = rows[e]; myc[i] = cols[e]; myv[i] = vals[e];
            atomicAdd(&hist_c[myc[i] >> KSH], 1);    // independent chains
            atomicAdd(&hist_r[myr[i] >> KSH], 1);
        } else myr[i] = -1;
    }
    __syncthreads();

    // ---- pass 0: keyed by col -> pairs_c ---------------------------------
    if (tid < NSUP) {
        const int v = hist_c[tid];
        lcur[tid] = v ? atomicAdd(&cur_c[tid], v) : 0;
    }
    __syncthreads();
#pragma unroll
    for (int i = 0; i < EPT; ++i) {
        if (myr[i] >= 0) {
            const int g = myc[i] >> KSH;
            const int pos = atomicAdd(&lcur[g], 1);
            pairs_c[pos] = make_int2(myr[i] | ((myc[i] & (KPS - 1)) << 20),
                                     __float_as_int(myv[i]));
        }
    }
    __syncthreads();

    // ---- pass 1: keyed by row -> pairs_r ---------------------------------
    if (tid < NSUP) {
        const int v = hist_r[tid];
        lcur[tid] = v ? atomicAdd(&cur_r[tid], v) : 0;
    }
    __syncthreads();
#pragma unroll
    for (int i = 0; i < EPT; ++i) {
        if (myr[i] >= 0) {
            const int g = myr[i] >> KSH;
            const int pos = atomicAdd(&lcur[g], 1);
            pairs_r[pos] = make_int2(myc[i] | ((myr[i] & (KPS - 1)) << 20),
                                     __float_as_int(myv[i]));
        }
    }
}

// ---------------------------------------------------------------------------
// Fused LDS counting-sort + register pull (round-6 proven version: direct
// consume, no filter). One 512-thread block per 128-row bucket (782 blocks,
// 33.5 KB LDS). Chunks of CAP edges: stage -> int-atomic hist -> wave-0 scan
// -> LDS scatter -> per-group register pull (16-lane group owns 4 rows; acc
// persists across chunks). 8/4/1 unroll ladder for memory-level parallelism.
// (Round-2 lesson: no LDS FP atomics — wave64 ds_add_f32 ~260 cy/instr.)
template <bool LN>
__global__ void __launch_bounds__(SPT, 6)
spmm_fused(const int* __restrict__ base,
           const int2* __restrict__ pairs,
           const unsigned short* __restrict__ src,
           const float* __restrict__ ego,
           const float* __restrict__ gamma,
           const float* __restrict__ beta,
           unsigned short* __restrict__ dstb,
           float* __restrict__ dstf)
{
    __shared__ int2 stage[CAP];                  // 16 KB
    __shared__ int2 sorted[CAP];                 // 16 KB
    __shared__ int cnt[KPS];                     // 512 B
    __shared__ int kbase[KPS];                   // 512 B
    __shared__ int kcur[KPS];                    // 512 B

    const int tid = threadIdx.x;
    const int sup = blockIdx.x;
    const int beg = base[sup];
    const int end = base[sup + 1];
    const int g = tid >> 4;                      // 32 groups of 16 lanes
    const int l = tid & 15;

    float4 acc[4];
#pragma unroll
    for (int i = 0; i < 4; ++i) acc[i] = make_float4(0.f, 0.f, 0.f, 0.f);

    if (tid < KPS) cnt[tid] = 0;
    __syncthreads();

    int c0 = beg;
    int csz = min(CAP, end - c0);
    for (int i = tid; i < csz; i += SPT) {
        const int2 v = pairs[c0 + i];
        stage[i] = v;
        atomicAdd(&cnt[(v.x >> 20) & (KPS - 1)], 1);
    }
    __syncthreads();

    while (csz > 0) {
        // ---- scan of 128 counters by wave 0 (lane owns 2 keys) -----------
        if (tid < 64) {
            const int ca = cnt[tid * 2];
            const int cb = cnt[tid * 2 + 1];
            const int tsum = ca + cb;
            int incl = tsum;
#pragma unroll
            for (int off = 1; off < 64; off <<= 1) {
                const int t = __shfl_up(incl, off, 64);
                if (tid >= off) incl += t;
            }
            const int run = incl - tsum;
            kbase[tid * 2] = run;          kcur[tid * 2] = run;
            kbase[tid * 2 + 1] = run + ca; kcur[tid * 2 + 1] = run + ca;
            cnt[tid * 2] = 0; cnt[tid * 2 + 1] = 0;   // ready for next hist
        }
        __syncthreads();

        // ---- counting-sort scatter (int LDS atomics: fast path) ----------
        for (int i = tid; i < csz; i += SPT) {
            const int2 v = stage[i];
            const int pos = atomicAdd(&kcur[(v.x >> 20) & (KPS - 1)], 1);
            sorted[pos] = v;
        }
        __syncthreads();

        // ---- consume (register pull, 8/4/1 ladder) + stage next chunk ----
        const int nc0 = c0 + csz;
        const int ncsz = min(CAP, end - nc0);

#pragma unroll
        for (int rr = 0; rr < 4; ++rr) {
            const int k = g * 4 + rr;
            int j = kbase[k];
            const int e = kcur[k];               // == end of key's run
            float4 a = acc[rr];
            for (; j + 8 <= e; j += 8) {
                int2 p[8]; ushort4 s[8];
#pragma unroll
                for (int u = 0; u < 8; ++u) p[u] = sorted[j + u];
#pragma unroll
                for (int u = 0; u < 8; ++u)
                    s[u] = ((const ushort4*)(src + (size_t)(p[u].x & 0x1FFFF) * EMB))[l];
#pragma unroll
                for (int u = 0; u < 8; ++u) {
                    const float v = __int_as_float(p[u].y);
                    a.x += v * bf2f(s[u].x); a.y += v * bf2f(s[u].y);
                    a.z += v * bf2f(s[u].z); a.w += v * bf2f(s[u].w);
                }
            }
            for (; j + 4 <= e; j += 4) {
                int2 p[4]; ushort4 s[4];
#pragma unroll
                for (int u = 0; u < 4; ++u) p[u] = sorted[j + u];
#pragma unroll
                for (int u = 0; u < 4; ++u)
                    s[u] = ((const ushort4*)(src + (size_t)(p[u].x & 0x1FFFF) * EMB))[l];
#pragma unroll
                for (int u = 0; u < 4; ++u) {
                    const float v = __int_as_float(p[u].y);
                    a.x += v * bf2f(s[u].x); a.y += v * bf2f(s[u].y);
                    a.z += v * bf2f(s[u].z); a.w += v * bf2f(s[u].w);
                }
            }
            for (; j < e; ++j) {
                const int2 p = sorted[j];
                const ushort4 s = ((const ushort4*)(src + (size_t)(p.x & 0x1FFFF) * EMB))[l];
                const float v = __int_as_float(p.y);
                a.x += v * bf2f(s.x); a.y += v * bf2f(s.y);
                a.z += v * bf2f(s.z); a.w += v * bf2f(s.w);
            }
            acc[rr] = a;
        }

        for (int i = tid; i < ncsz; i += SPT) {
            const int2 v = pairs[nc0 + i];
            stage[i] = v;
            atomicAdd(&cnt[(v.x >> 20) & (KPS - 1)], 1);
        }
        c0 = nc0; csz = ncsz;
        __syncthreads();
    }

    // ---- epilogue -------------------------------------------------------
    const int r0 = sup * KPS + g * 4;
    if (!LN) {
#pragma unroll
        for (int rr = 0; rr < 4; ++rr) {
            const int row = r0 + rr;
            if (row < N_TOTAL) {
                ushort4 o;
                o.x = f2bf(acc[rr].x); o.y = f2bf(acc[rr].y);
                o.z = f2bf(acc[rr].z); o.w = f2bf(acc[rr].w);
                ((ushort4*)dstb)[(size_t)row * 16 + l] = o;
            }
        }
    } else {
        const float4 gm = ((const float4*)gamma)[l];
        const float4 bt = ((const float4*)beta)[l];
#pragma unroll
        for (int rr = 0; rr < 4; ++rr) {
            const int row = r0 + rr;
            const float4 a = acc[rr];
            float s  = a.x + a.y + a.z + a.w;
            float s2 = a.x * a.x + a.y * a.y + a.z * a.z + a.w * a.w;
#pragma unroll
            for (int m = 1; m <= 8; m <<= 1) {   // reduce across the 16-lane group
                s  += __shfl_xor(s,  m, 64);
                s2 += __shfl_xor(s2, m, 64);
            }
            const float mu  = s * (1.0f / EMB);
            const float var = s2 * (1.0f / EMB) - mu * mu;
            const float inv = rsqrtf(var + LN_EPS);
            if (row < N_TOTAL) {
                const float4 eg = ((const float4*)(ego + (size_t)row * EMB))[l];
                float4 o;
                o.x = (a.x - mu) * inv * gm.x + bt.x + eg.x;
                o.y = (a.y - mu) * inv * gm.y + bt.y + eg.y;
                o.z = (a.z - mu) * inv * gm.z + bt.z + eg.z;
                o.w = (a.w - mu) * inv * gm.w + bt.w + eg.w;
                ((float4*)(dstf + (size_t)row * EMB))[l] = o;
            }
        }
    }
}

// ---------------------------------------------------------------------------
// Fallback (round-1) atomic scatter path, fp32, used only if ws too small.
__global__ void transform_kernel(const float* __restrict__ x,
                                 const float* __restrict__ W,
                                 const float* __restrict__ filt,
                                 const float* __restrict__ par,
                                 float* __restrict__ out, int nrows)
{
    __shared__ float Ws[EMB * EMB];
    const int tid = threadIdx.x;
    for (int i = tid; i < EMB * EMB; i += blockDim.x) Ws[i] = W[i];
    __syncthreads();
    const float c = par[0] * par[1];
    const int lane = tid & 63;
    const int wave = tid >> 6;
    const int r0 = blockIdx.x * 32;
    for (int rr = wave; rr < 32; rr += 4) {
        const int r = r0 + rr;
        if (r >= nrows) break;
        const float xv = x[(size_t)r * EMB + lane];
        float acc = 0.f;
#pragma unroll
        for (int k = 0; k < EMB; ++k) {
            const float xk = __shfl(xv, k, 64);
            acc += xk * Ws[k * EMB + lane];
        }
        out[(size_t)r * EMB + lane] = c * filt[r] * acc + xv;
    }
}

__global__ void spmm_scatter(const int* __restrict__ src_idx,
                             const int* __restrict__ dst_idx,
                             const float* __restrict__ vals,
                             const float* __restrict__ src,
                             float* __restrict__ dst, int nnz)
{
    const long long t = (long long)blockIdx.x * blockDim.x + threadIdx.x;
    const int e = (int)(t >> 4);
    const int l = (int)(t & 15);
    if (e >= nnz) return;
    const int s = src_idx[e];
    const int d = dst_idx[e];
    const float v = vals[e];
    const float4 xv = ((const float4*)(src + (size_t)s * EMB))[l];
    float* dp = dst + (size_t)d * EMB + l * 4;
    atomicAdd(dp + 0, v * xv.x);
    atomicAdd(dp + 1, v * xv.y);
    atomicAdd(dp + 2, v * xv.z);
    atomicAdd(dp + 3, v * xv.w);
}

__global__ void ln_residual(const float* y,
                            const float* __restrict__ ego,
                            const float* __restrict__ gamma,
                            const float* __restrict__ beta,
                            float* out, int nrows)
{
    const int lane = threadIdx.x & 63;
    const int wave = threadIdx.x >> 6;
    const int r = blockIdx.x * 4 + wave;
    if (r >= nrows) return;
    const float v = y[(size_t)r * EMB + lane];
    float s = v, s2 = v * v;
#pragma unroll
    for (int off = 32; off > 0; off >>= 1) {
        s  += __shfl_down(s,  off, 64);
        s2 += __shfl_down(s2, off, 64);
    }
    s  = __shfl(s,  0, 64);
    s2 = __shfl(s2, 0, 64);
    const float mu  = s * (1.0f / EMB);
    const float var = s2 * (1.0f / EMB) - mu * mu;
    const float inv = rsqrtf(var + LN_EPS);
    out[(size_t)r * EMB + lane] =
        (v - mu) * inv * gamma[lane] + beta[lane] + ego[(size_t)r * EMB + lane];
}

extern "C" void kernel_launch(void* const* d_in, const int* in_sizes, int n_in,
                              void* d_out, int out_size, void* d_ws, size_t ws_size,
                              hipStream_t stream)
{
    const float* ego     = (const float*)d_in[0];
    const int*   rows    = (const int*)  d_in[1];
    const int*   cols    = (const int*)  d_in[2];
    const float* vals    = (const float*)d_in[3];
    const float* w_uu    = (const float*)d_in[4];
    const float* filt_uu = (const float*)d_in[5];
    const float* par_uu  = (const float*)d_in[6];
    const float* w_ii    = (const float*)d_in[7];
    const float* filt_ii = (const float*)d_in[8];
    const float* par_ii  = (const float*)d_in[9];
    const float* gamma   = (const float*)d_in[10];
    const float* beta    = (const float*)d_in[11];
    float* out = (float*)d_out;
    const int nnz = in_sizes[1];

    const size_t emb_elems = (size_t)N_TOTAL * EMB;
    const size_t emb_bytes = emb_elems * sizeof(float);
    const size_t bf_bytes  = emb_elems * sizeof(unsigned short);

    // fast path: 2 bf16 tables + TWO pairs arrays + counters (~77.0 MB,
    // the bound proven available in earlier rounds)
    const size_t need = 2 * bf_bytes + 2 * (size_t)nnz * sizeof(int2)
                        + (size_t)(6 * (NSUP + 1)) * sizeof(int);

    if (ws_size >= need) {
        // ---- fast path: stage-free dual build + fused LDS-sort + pull ----
        unsigned short* ego2b = (unsigned short*)d_ws;    // 12.8 MB
        unsigned short* hb    = ego2b + emb_elems;        // 12.8 MB
        int2* pairs_c = (int2*)(hb + emb_elems);          // 25.6 MB
        int2* pairs_r = pairs_c + nnz;                    // 25.6 MB
        int*  cnt_c  = (int*)(pairs_r + nnz);
        int*  cnt_r  = cnt_c + NSUP;
        int*  base_c = cnt_r + NSUP;
        int*  cur_c  = base_c + (NSUP + 1);
        int*  base_r = cur_c + NSUP;
        int*  cur_r  = base_r + (NSUP + 1);

        hipMemsetAsync(cnt_c, 0, 2 * NSUP * sizeof(int), stream);

        hist_sup<<<512, 256, 0, stream>>>(rows, cols, cnt_r, cnt_c, nnz);
        scan_sup<<<2, 1024, 0, stream>>>(cnt_c, base_c, cur_c,
                                         cnt_r, base_r, cur_r);

        transform_tile<<<N_TOTAL / TR_ROWS, 256, 0, stream>>>(
            ego, w_uu, filt_uu, par_uu, w_ii, filt_ii, par_ii, ego2b);

        const int l1b = (nnz + EPB - 1) / EPB;
        build_both<<<l1b, BLT, 0, stream>>>(rows, cols, vals,
                                            cur_c, pairs_c, cur_r, pairs_r, nnz);

        // Pass 1: key = col, payload = row.  h[c] = sum val*ego2[r]  (bf16)
        spmm_fused<false><<<NSUP, SPT, 0, stream>>>(
            base_c, pairs_c, ego2b, nullptr, nullptr, nullptr, hb, nullptr);

        // Pass 2: key = row, payload = col.  out = LN(A h) + ego, fused.
        spmm_fused<true><<<NSUP, SPT, 0, stream>>>(
            base_r, pairs_r, hb, ego, gamma, beta, nullptr, out);
    } else {
        // ---------------- fallback: atomic scatter (round-1, fp32) -------
        float* ego2 = (float*)d_ws;
        float* h    = ego2 + emb_elems;
        hipMemsetAsync(h,   0, emb_bytes, stream);
        hipMemsetAsync(out, 0, emb_bytes, stream);

        transform_kernel<<<(N_USERS + 31) / 32, 256, 0, stream>>>(
            ego, w_uu, filt_uu, par_uu, ego2, N_USERS);
        transform_kernel<<<(N_ITEMS + 31) / 32, 256, 0, stream>>>(
            ego + (size_t)N_USERS * EMB, w_ii, filt_ii, par_ii,
            ego2 + (size_t)N_USERS * EMB, N_ITEMS);

        const long long thr = (long long)nnz * 16;
        const int sblocks = (int)((thr + 255) / 256);
        spmm_scatter<<<sblocks, 256, 0, stream>>>(rows, cols, vals, ego2, h, nnz);
        spmm_scatter<<<sblocks, 256, 0, stream>>>(cols, rows, vals, h, out, nnz);

        const int rb = (N_TOTAL + 3) / 4;
        ln_residual<<<rb, 256, 0, stream>>>(out, ego, gamma, beta, out, N_TOTAL);
    }
}